// Round 14
// baseline (2207.980 us; speedup 1.0000x reference)
//
#include <hip/hip_runtime.h>
#include <stdint.h>

typedef __attribute__((ext_vector_type(8))) __bf16 bf16x8;
typedef __attribute__((ext_vector_type(4))) float f32x4;
typedef __attribute__((ext_vector_type(4))) unsigned u32x4;

#define DEVI static __device__ __forceinline__
#define SENT 0xFFFFFFFFu

DEVI bf16x8 bzero8(){ bf16x8 r;
#pragma unroll
  for (int i=0;i<8;++i) r[i]=(__bf16)0.0f; return r; }

DEVI bf16x8 ld8(const __bf16* p){ return *(const bf16x8*)p; }
DEVI void st8(__bf16* p, bf16x8 v){ *(bf16x8*)p = v; }

DEVI f32x4 MFMA(bf16x8 a, bf16x8 b, f32x4 c){
  return __builtin_amdgcn_mfma_f32_16x16x32_bf16(a, b, c, 0, 0, 0);
}

DEVI float sigf(float x){ return 1.0f/(1.0f+__expf(-x)); }

// ---- agent-scope (MALL) relaxed atomics ----
DEVI void ast(unsigned* p, unsigned v){ __hip_atomic_store(p, v, __ATOMIC_RELAXED, __HIP_MEMORY_SCOPE_AGENT); }
DEVI unsigned ald1(const unsigned* p){ return __hip_atomic_load(p, __ATOMIC_RELAXED, __HIP_MEMORY_SCOPE_AGENT); }

DEVI unsigned packbf(float a, float b){
  union { __bf16 h[2]; unsigned u; } x; x.h[0]=(__bf16)a; x.h[1]=(__bf16)b; return x.u;
}
DEVI float bflo(unsigned u){ return __builtin_bit_cast(float, u<<16); }
DEVI float bfhi(unsigned u){ return __builtin_bit_cast(float, u & 0xffff0000u); }

DEVI unsigned bad4(u32x4 v){ return (v[0]==SENT)|(v[1]==SENT)|(v[2]==SENT)|(v[3]==SENT); }

// agent-coherent 16B load (bypass L1+L2, read MALL)
DEVI u32x4 ald4(const void* p){
  u32x4 v;
  asm volatile("global_load_dwordx4 %0, %1, off sc0 sc1\n\ts_waitcnt vmcnt(0)"
               : "=&v"(v) : "v"(p) : "memory");
  return v;
}
DEVI u32x4 poll4(const void* p){
  u32x4 v = ald4(p);
  while (bad4(v)){ __builtin_amdgcn_s_sleep(1); v = ald4(p); }
  return v;
}
DEVI void ald4x2(const void* p, u32x4& a, u32x4& b){
  asm volatile("global_load_dwordx4 %0, %2, off sc0 sc1\n\t"
               "global_load_dwordx4 %1, %2, off offset:16 sc0 sc1\n\t"
               "s_waitcnt vmcnt(0)"
               : "=&v"(a), "=&v"(b) : "v"(p) : "memory");
}
DEVI void poll4x2(const void* p, u32x4& a, u32x4& b){
  ald4x2(p, a, b);
  while (bad4(a) | bad4(b)){ __builtin_amdgcn_s_sleep(1); ald4x2(p, a, b); }
}

DEVI void drainvm(){ asm volatile("s_waitcnt vmcnt(0)" ::: "memory"); }

// monotone-epoch flag barrier (slots stride 16 dwords)
DEVI void flagbar(unsigned* slots, int nblk, int bk, unsigned ep){
  __syncthreads();
  if (threadIdx.x == 0) ast(slots + (size_t)bk*16, ep);
  if ((int)threadIdx.x < nblk){
    const unsigned* sp = slots + (size_t)threadIdx.x*16;
    while (ald1(sp) < ep) __builtin_amdgcn_s_sleep(1);
  }
  __syncthreads();
}

// ---------------- packing ----------------
DEVI void packGroup(const float* W, int Nsrc, int Kreal, int NT, __bf16* dst, long g){
  int kt = (int)(g / (NT*64));
  int rem = (int)(g % (NT*64));
  int nt = rem >> 6, ln = rem & 63;
  int row = nt*16 + (ln & 15);
  int col = kt*32 + ((ln >> 4) << 3);
  bf16x8 v = bzero8();
  if (row < Nsrc){
#pragma unroll
    for (int j=0;j<8;++j){ int c = col + j; if (c < Kreal) v[j] = (__bf16)W[(long)row*Kreal + c]; }
  }
  st8(dst + g*8, v);
}

DEVI void packGroupCat(const float* Wih, const float* Whh, __bf16* dst, long g){
  int kt = (int)(g / (128*64));
  int rem = (int)(g % (128*64));
  int nt = rem >> 6, ln = rem & 63;
  int prow = nt*16 + (ln & 15);
  int src = (prow & 3)*512 + (prow >> 2);
  int col = kt*32 + ((ln >> 4) << 3);
  bf16x8 v;
  if (col < 32){
#pragma unroll
    for (int j=0;j<8;++j) v[j] = (__bf16)Wih[(long)src*32 + col + j];
  } else {
#pragma unroll
    for (int j=0;j<8;++j) v[j] = (__bf16)Whh[(long)src*512 + (col-32) + j];
  }
  st8(dst + g*8, v);
}

// pyramid-layer pack work item (pf/pb/bsum/pwhh); total 1314816 items
#define NPACKITEMS 1314816L
DEVI void packPencItem(long g,
    const float* Wf, const float* Wb, const float* WhF, const float* WhB,
    const float* bihf, const float* bhhf, const float* bihb, const float* bhhb,
    __bf16* pf, __bf16* pb, float* bsum, __bf16* pwhh)
{
  const long nW = 64L*128*64;
  if (g < nW){ packGroup(Wf, 2048, 2048, 128, pf, g); return; }
  g -= nW;
  if (g < nW){ packGroup(Wb, 2048, 2048, 128, pb, g); return; }
  g -= nW;
  if (g < 2048){ bsum[g] = bihf[g] + bhhf[g]; return; }
  g -= 2048;
  if (g < 2048){ bsum[2048+g] = bihb[g] + bhhb[g]; return; }
  g -= 2048;
  if (g < 262144){
    int lane = (int)(g & 63);
    int f    = (int)((g >> 6) & 31);
    int w    = (int)((g >> 11) & 3);
    int slot = (int)((g >> 13) & 15);
    int dir  = (int)((g >> 17) & 1);
    int kt = f >> 1, nt = f & 1;
    int row16 = lane & 15, kch = lane >> 4;
    int srow = w*512 + slot*32 + nt*16 + row16;
    int scol = kt*32 + kch*8;
    const float* W = dir ? WhB : WhF;
    bf16x8 v;
#pragma unroll
    for (int j=0;j<8;++j) v[j] = (__bf16)W[(long)srow*512 + scol + j];
    st8(pwhh + g*8, v);
  }
}

// sentinel decoder HB bufs 1..3 + zero flag/counter region
__global__ void initK(unsigned* bar, unsigned* hb){
  int g = blockIdx.x*256 + threadIdx.x;
  if (g < 3072){ bar[g] = 0u; return; }
  g -= 3072;
  if (g < 6144){ hb[2048 + g] = SENT; return; }   // HB bufs 1..3 (buf0 = h0b)
}

__global__ void packSmallK(const float* __restrict__ xs, const float* __restrict__ eWih,
    const float* __restrict__ eWhh, const float* __restrict__ ebih, const float* __restrict__ ebhh,
    const float* __restrict__ attnW,
    __bf16* __restrict__ xsb, __bf16* __restrict__ wcatp, float* __restrict__ biasc,
    __bf16* __restrict__ attnp)
{
  long g = (long)blockIdx.x*blockDim.x + threadIdx.x;
  const long nWcat = 17L*128*64;
  const long nXs   = 92160;
  const long nBias = 2048;
  const long nAttn = 33L*2*64;
  if (g < nWcat){ packGroupCat(eWih, eWhh, wcatp, g); return; }
  g -= nWcat;
  if (g < nXs){
    const float* s = xs + g*8; bf16x8 v;
#pragma unroll
    for (int j=0;j<8;++j) v[j] = (__bf16)s[j];
    st8(xsb + g*8, v); return;
  }
  g -= nXs;
  if (g < nBias){ int src = ((int)g & 3)*512 + ((int)g >> 2); biasc[g] = ebih[src] + ebhh[src]; return; }
  g -= nBias;
  if (g < nAttn){ packGroup(attnW, 30, 1032, 2, attnp, g); return; }
}

// standalone pack (layer 0 only): Wih/biases/HPYR init/Whh reg-frag layout
__global__ void packPencK(const float* __restrict__ Wf, const float* __restrict__ Wb,
    const float* __restrict__ WhF, const float* __restrict__ WhB,
    const float* __restrict__ bihf, const float* __restrict__ bhhf,
    const float* __restrict__ bihb, const float* __restrict__ bhhb,
    __bf16* __restrict__ pf, __bf16* __restrict__ pb, float* __restrict__ bsum,
    __bf16* __restrict__ pwhh, unsigned* __restrict__ hpy)
{
  long g = (long)blockIdx.x*blockDim.x + threadIdx.x;
  if (g < 8192){
    hpy[g] = ((g >> 10) & 3) ? SENT : 0u;
    return;
  }
  g -= 8192;
  if (g < NPACKITEMS)
    packPencItem(g, Wf, Wb, WhF, WhB, bihf, bhhf, bihb, bhhb, pf, pb, bsum, pwhh);
}

// ---------------- encoder step ----------------
__global__ __launch_bounds__(256, 1) void encStepK(
    const __bf16* __restrict__ xsb,
    __bf16* __restrict__ henc,
    float* __restrict__ cenc,
    const __bf16* __restrict__ wcatp,
    const float* __restrict__ biasc,
    const int* __restrict__ xlen,
    __bf16* __restrict__ ctx,
    int t)
{
  __shared__ float glds[64][260];
  const int tid = threadIdx.x;
  const int w = tid >> 6, ln = tid & 63;
  const int m0 = blockIdx.x * 64;
  const int nb = blockIdx.y;
  f32x4 acc[16];
#pragma unroll
  for (int i=0;i<16;++i) acc[i] = (f32x4){0.f,0.f,0.f,0.f};

  const int arow = m0 + w*16 + (ln & 15);
  const int kc = (ln >> 4) << 3;
  const int ktEnd = (t == 0) ? 1 : 17;
  for (int kt = 0; kt < ktEnd; ++kt){
    bf16x8 a;
    if (kt == 0) a = ld8(xsb + ((long)t*1920 + arow)*32 + kc);
    else         a = ld8(henc + (long)arow*512 + (kt-1)*32 + kc);
    const __bf16* bp = wcatp + (((long)kt*128 + nb*16)*64 + ln)*8;
#pragma unroll
    for (int n2 = 0; n2 < 16; ++n2){
      bf16x8 b = ld8(bp + (long)n2*512);
      acc[n2] = MFMA(a, b, acc[n2]);
    }
  }
  const int r4 = (ln >> 4) << 2;
#pragma unroll
  for (int n2 = 0; n2 < 16; ++n2){
#pragma unroll
    for (int r = 0; r < 4; ++r)
      glds[w*16 + r4 + r][n2*16 + (ln & 15)] = acc[n2][r];
  }
  __syncthreads();
  for (int it = 0; it < 16; ++it){
    int idx = tid + it*256;
    int mrow = idx >> 6, hcl = idx & 63;
    int n = m0 + mrow;
    int hcg = nb*64 + hcl;
    float ig = glds[mrow][hcl*4+0] + biasc[nb*256 + hcl*4+0];
    float fg = glds[mrow][hcl*4+1] + biasc[nb*256 + hcl*4+1];
    float gg = glds[mrow][hcl*4+2] + biasc[nb*256 + hcl*4+2];
    float og = glds[mrow][hcl*4+3] + biasc[nb*256 + hcl*4+3];
    float c_old = (t == 0) ? 0.0f : cenc[(long)n*512 + hcg];
    float cn = sigf(fg)*c_old + sigf(ig)*tanhf(gg);
    float h  = sigf(og)*tanhf(cn);
    cenc[(long)n*512 + hcg] = cn;
    henc[(long)n*512 + hcg] = (__bf16)h;
    if (xlen[n] - 1 == t){
      ctx[(long)n*1024 + hcg]       = (__bf16)h;
      ctx[(long)n*1024 + 512 + hcg] = (__bf16)cn;
    }
  }
}

// ---------------- pyramid input GEMM ----------------
__global__ __launch_bounds__(1024) void pencInK(
   const __bf16* __restrict__ inb,
   const __bf16* __restrict__ wpf, const __bf16* __restrict__ wpb,
   const float* __restrict__ bsum,
   float* __restrict__ xpf, float* __restrict__ xpb,
   int M)
{
  const int tid = threadIdx.x, ln = tid & 63, wv = tid >> 6;
  const int rg = wv >> 2, cg = wv & 3;
  const int dir = blockIdx.z;
  const int m0 = blockIdx.x*64 + rg*16;
  const int nb = blockIdx.y;
  const __bf16* wp = dir ? wpb : wpf;
  float* xp = dir ? xpb : xpf;
  const float* bs = bsum + dir*2048;
  f32x4 acc[4];
#pragma unroll
  for (int i=0;i<4;++i) acc[i] = (f32x4){0.f,0.f,0.f,0.f};
  const int arow = m0 + (ln & 15);
  const int kc = (ln >> 4) << 3;
  const bool aok = arow < M;
  for (int kt = 0; kt < 64; ++kt){
    bf16x8 a = aok ? ld8(inb + (long)arow*2048 + kt*32 + kc) : bzero8();
    const __bf16* bp = wp + (((long)kt*128 + nb*16 + cg*4)*64 + ln)*8;
#pragma unroll
    for (int q = 0; q < 4; ++q){
      bf16x8 b = ld8(bp + (long)q*512);
      acc[q] = MFMA(a, b, acc[q]);
    }
  }
  const int r4 = (ln >> 4) << 2;
#pragma unroll
  for (int q = 0; q < 4; ++q){
    int col = (nb*16 + cg*4 + q)*16 + (ln & 15);
#pragma unroll
    for (int r = 0; r < 4; ++r){
      int rowo = m0 + r4 + r;
      if (rowo < M) xp[(long)rowo*2048 + col] = acc[q][r] + bs[col];
    }
  }
}

// ---------------- pyramid recurrence (+ hidden next-layer packing) ----------------
__global__ __launch_bounds__(256, 1) void pyrRecK(
  const __bf16* __restrict__ pwhh,
  const float* __restrict__ xpf, const float* __restrict__ xpb,
  __bf16* __restrict__ hbuf,
  __bf16* __restrict__ outb,
  float* __restrict__ outf,
  float* __restrict__ h0f, __bf16* __restrict__ h0b,
  int T, int isLast, int L, int hasPack,
  const float* __restrict__ nWf, const float* __restrict__ nWb,
  const float* __restrict__ nWhF, const float* __restrict__ nWhB,
  const float* __restrict__ nbihf, const float* __restrict__ nbhhf,
  const float* __restrict__ nbihb, const float* __restrict__ nbhhb,
  __bf16* __restrict__ pf2, __bf16* __restrict__ pb2,
  float* __restrict__ bsum2, __bf16* __restrict__ pwhh2,
  unsigned* __restrict__ cnt, unsigned* __restrict__ slotsBase)
{
  __shared__ __align__(16) __bf16 hsL[2][4*528];
  __shared__ float glds[4][4][32];
  const int tid = threadIdx.x, ln = tid & 63, w = tid >> 6;
  const int bk = blockIdx.x;

  if (bk >= 32){
    if (!hasPack) return;
    if (tid == 0){ while (ald1(cnt) < 32u) __builtin_amdgcn_s_sleep(2); }
    __syncthreads();
    long g = (long)(bk - 32)*256 + tid;
    if (g < NPACKITEMS)
      packPencItem(g, nWf, nWb, nWhF, nWhB, nbihf, nbhhf, nbihb, nbhhb, pf2, pb2, bsum2, pwhh2);
    return;
  }

  const int dir = bk >> 4, slot = bk & 15;
  const int hc0 = slot * 32;
  const float* xp = dir ? xpb : xpf;
  unsigned* hbu = (unsigned*)hbuf;

  bf16x8 BF[32];
  {
    const __bf16* wb = pwhh + ((((size_t)(dir*16 + slot)*4 + w)*32)*64 + ln)*8;
#pragma unroll
    for (int f = 0; f < 32; ++f) BF[f] = ld8(wb + (size_t)f*512);
  }
  drainvm();
  __syncthreads();
  if (tid == 0)
    __hip_atomic_fetch_add(cnt, 1u, __ATOMIC_RELAXED, __HIP_MEMORY_SCOPE_AGENT);
  if (tid < 64){
    int b = tid >> 4, i = tid & 15;
#pragma unroll
    for (int bu = 0; bu < 4; ++bu)
      ast(hbu + ((size_t)(dir*4 + bu)*4 + b)*256 + (hc0 >> 1) + i, bu == 0 ? 0u : SENT);
  }
  flagbar(slotsBase + dir*256, 16, slot, (unsigned)(L+1));
  __builtin_amdgcn_s_setprio(1);

  const int arow = ln & 15;
  const int kc = (ln >> 4) << 3;
  float cv = 0.0f;
  float x0=0.f,x1=0.f,x2=0.f,x3=0.f;
  if (tid < 128){
    int pos0 = dir ? (T-1) : 0;
    const float* xr = xp + ((size_t)((tid>>5)*T + pos0))*2048 + hc0 + (tid & 31);
    x0 = xr[0]; x1 = xr[512]; x2 = xr[1024]; x3 = xr[1536];
  }

  for (int t = 0; t < T; ++t){
    int cur = t & 3, nxt = (t+1) & 3, clr = (t+2) & 3;
    int pos = dir ? (T-1-t) : t;
    {
      u32x4 v = poll4((const char*)hbuf + (size_t)(dir*4 + cur)*4096 + tid*16);
      int e0 = tid*8, r = e0 >> 9, o = e0 & 511;
      *(u32x4*)(hsL[t & 1] + r*528 + o) = v;
    }
    __syncthreads();
    if (tid < 64){
      int b = tid >> 4, i = tid & 15;
      ast(hbu + ((size_t)(dir*4 + clr)*4 + b)*256 + (hc0 >> 1) + i, SENT);
    }
    const __bf16* hs = hsL[t & 1];
    f32x4 a0 = {0.f,0.f,0.f,0.f}, a1 = a0, a2 = a0, a3 = a0;
#pragma unroll
    for (int kt = 0; kt < 16; kt += 2){
      bf16x8 aA = (arow < 4) ? ld8(hs + arow*528 + kt*32 + kc) : bzero8();
      bf16x8 aB = (arow < 4) ? ld8(hs + arow*528 + (kt+1)*32 + kc) : bzero8();
      a0 = MFMA(aA, BF[kt*2+0], a0);
      a1 = MFMA(aA, BF[kt*2+1], a1);
      a2 = MFMA(aB, BF[kt*2+2], a2);
      a3 = MFMA(aB, BF[kt*2+3], a3);
    }
    a0 += a2; a1 += a3;
    float xn0=0.f,xn1=0.f,xn2=0.f,xn3=0.f;
    if (t+1 < T && tid < 128){
      int pos2 = dir ? (T-2-t) : (t+1);
      const float* xr = xp + ((size_t)((tid>>5)*T + pos2))*2048 + hc0 + (tid & 31);
      xn0 = xr[0]; xn1 = xr[512]; xn2 = xr[1024]; xn3 = xr[1536];
    }
    if (ln < 16){
#pragma unroll
      for (int r=0;r<4;++r){ glds[w][r][ln] = a0[r]; glds[w][r][16+ln] = a1[r]; }
    }
    __syncthreads();
    if (tid < 128){
      int b = tid >> 5, hcl = tid & 31, hcg = hc0 + hcl;
      float ig = glds[0][b][hcl] + x0;
      float fg = glds[1][b][hcl] + x1;
      float gg = glds[2][b][hcl] + x2;
      float og = glds[3][b][hcl] + x3;
      cv = sigf(fg)*cv + sigf(ig)*tanhf(gg);
      float h = sigf(og)*tanhf(cv);
      float hn = __shfl_down(h, 1);
      if (!(hcl & 1))
        ast(hbu + ((size_t)(dir*4 + nxt)*4 + b)*256 + (hcg >> 1), packbf(h, hn));
      if (!isLast){
        outb[((long)(b*T + pos))*1024 + dir*512 + hcg] = (__bf16)h;
      } else {
        outf[((long)(b*T + pos))*1024 + dir*512 + hcg] = h;
        if (t == T-1){
          h0f[b*1024 + dir*512 + hcg] = h;
          h0b[b*1024 + dir*512 + hcg] = (__bf16)h;
        }
      }
    }
    x0=xn0; x1=xn1; x2=xn2; x3=xn3;
  }
}

// ---------------- M precompute: M[b][t][c] = sum_d combW[c][8+d]*encOut[b][t][d] ----------------
__global__ __launch_bounds__(256) void precMK(const float* __restrict__ combW,
    const float* __restrict__ encOut, __bf16* __restrict__ Mb)
{
  __shared__ float eo[1024];
  int bt = blockIdx.x;
  int b = bt / 30, t = bt % 30;
  int tid = threadIdx.x;
  for (int i = tid; i < 1024; i += 256) eo[i] = encOut[((long)b*30 + t)*1024 + i];
  __syncthreads();
#pragma unroll 1
  for (int cc = 0; cc < 2; ++cc){
    int c = tid*2 + cc;
    const f32x4* wr4 = (const f32x4*)(combW + (long)c*1032 + 8);
    float s = 0.f;
    for (int d = 0; d < 256; ++d){
      f32x4 wv = wr4[d];
      s += wv[0]*eo[d*4] + wv[1]*eo[d*4+1] + wv[2]*eo[d*4+2] + wv[3]*eo[d*4+3];
    }
    Mb[((long)b*30 + t)*512 + c] = (__bf16)s;
  }
}

// ---------------- decoder: 32 blocks, ONE exchange/step (M-trick) ----------------
DEVI bf16x8 dfrag(const __bf16* base, const __bf16* inp, int row, int kt, int kc, int stride){
  if (row >= 4) return bzero8();
  int k = kt*32 + kc;
  if (k == 0) return ld8(inp + row*8);
  int off = k - 8;
  return (off < 1024) ? ld8(base + row*stride + off) : bzero8();
}

__global__ __launch_bounds__(256, 1) void decoderK(
  const float* __restrict__ gWih,   // [3072][512]
  const float* __restrict__ gWhh,   // [3072][1024]
  const float* __restrict__ gbih, const float* __restrict__ gbhh,
  const float* __restrict__ combW,      // [512][1032]
  const float* __restrict__ combBias,   // [512]
  const float* __restrict__ attnBias,
  const float* __restrict__ outW, const float* __restrict__ outBias,
  const __bf16* __restrict__ attnP,
  const __bf16* __restrict__ Mb,        // [4][30][512] bf16
  const float* __restrict__ h0f,
  __bf16* __restrict__ HB,              // [4buf][4][1024]
  float* __restrict__ dout)
{
  __shared__ __align__(16) __bf16 giL[96*512];     // 96 KB XOR-swizzled
  __shared__ __align__(16) __bf16 outWL[8*1040];   // padded stride 520 dwords
  __shared__ __align__(16) __bf16 hL[4*1040];      // padded stride 520 dwords
  __shared__ __align__(16) __bf16 xL[4][528];
  __shared__ __align__(16) __bf16 WcIT[8][520];    // transposed comb_W[:, :8]
  __shared__ __align__(16) __bf16 inpL[32];
  __shared__ float awL[4][32];
  __shared__ float redL[4][8];
  __shared__ float ghL[3][4][32];
  __shared__ float giO[3][4][32];
  __shared__ float biL[3][32], bhL[3][32];
  __shared__ float abL[30];
  __shared__ float cbAllL[512];

  const int tid = threadIdx.x, ln = tid & 63, w = tid >> 6;
  const int slot = blockIdx.x;          // 0..31
  const int hc0 = slot * 32;
  unsigned* HBu = (unsigned*)HB;

  // gi weights -> LDS (3 gates x 32 own cols = 96 rows x 512, XOR swizzled)
  for (int it = 0; it < 24; ++it){
    int g = it*256 + tid;
    int rho = g >> 6, c8 = g & 63;
    int gate = rho >> 5, r = rho & 31;
    const float* s = gWih + ((long)(gate*1024 + hc0 + r))*512 + c8*8;
    bf16x8 v;
#pragma unroll
    for (int j=0;j<8;++j) v[j] = (__bf16)s[j];
    st8((__bf16*)((char*)giL + ((rho*1024 + c8*16) ^ ((rho & 7) << 4))), v);
  }
  for (int it = 0; it < 32; ++it){
    int g = it*256 + tid;
    int r = g >> 10, c = g & 1023;
    outWL[r*1040 + c] = (__bf16)outW[g];
  }
  for (int idx = tid; idx < 4096; idx += 256){
    int c = idx >> 3, j = idx & 7;
    WcIT[j][c] = (__bf16)combW[(long)c*1032 + j];
  }
  for (int idx = tid; idx < 512; idx += 256) cbAllL[idx] = combBias[idx];
  if (tid < 96){
    int g2 = tid >> 5, l = tid & 31;
    biL[g2][l] = gbih[g2*1024 + hc0 + l];
    bhL[g2][l] = gbhh[g2*1024 + hc0 + l];
  }
  if (tid < 30) abL[tid] = attnBias[tid];

  const int row = ln & 15, kc = (ln >> 4) << 3;
  // bigF: w0 -> attn frags [2x33]; w1-3 -> gh frags for gate w-1 [2x32]
  bf16x8 bigF[66];
  if (w == 0){
#pragma unroll
    for (int nt = 0; nt < 2; ++nt)
#pragma unroll
      for (int kt = 0; kt < 33; ++kt)
        bigF[nt*33 + kt] = ld8(attnP + (((size_t)kt*2 + nt)*64 + ln)*8);
  } else {
    int gate = w - 1;
#pragma unroll
    for (int nt = 0; nt < 2; ++nt)
#pragma unroll
      for (int kt = 0; kt < 32; ++kt){
        const float* s = gWhh + ((long)(gate*1024 + hc0 + nt*16 + row))*1024 + kt*32 + kc;
        bf16x8 v;
#pragma unroll
        for (int j=0;j<8;++j) v[j] = (__bf16)s[j];
        bigF[nt*33 + kt] = v;
      }
  }

  float hold = 0.f;
  if (tid < 128) hold = h0f[(tid>>5)*1024 + hc0 + (tid & 31)];
  __syncthreads();

  for (int s = 0; s <= 32; ++s){
    int cur = s & 3, nxt = (s+1) & 3, clr = (s+2) & 3;
    // poll h(s) -> hL (padded remap, element units)
    {
      u32x4 q0, q1;
      poll4x2((const char*)HB + (size_t)cur*8192 + tid*32, q0, q1);
      int e0 = tid*16, r0 = e0 >> 10, o0 = e0 & 1023;
      u32x4* d = (u32x4*)(hL + r0*1040 + o0);
      d[0] = q0; d[1] = q1;
    }
    __syncthreads();
    // re-sentinel step s+2 h-buffer (own cols)
    if (tid < 64){
      int b = tid >> 4, i = tid & 15;
      ast(HBu + ((size_t)clr*4 + b)*512 + (hc0 >> 1) + i, SENT);
    }
    if (s == 0){
      if (tid < 32) inpL[tid] = (__bf16)0.0f;
      __syncthreads();
    } else {
      // logits: conflict-free interleaved dot-product (padded strides)
      int o = tid >> 3, sl = tid & 7;
      int b = o >> 3, l = o & 7;
      const unsigned* hrow = (const unsigned*)hL + b*520;
      const unsigned* wrow = (const unsigned*)outWL + l*520;
      float p = 0.f;
#pragma unroll 8
      for (int j = 0; j < 64; ++j){
        unsigned u = hrow[sl + 8*j], t2 = wrow[sl + 8*j];
        p += bflo(u)*bflo(t2) + bfhi(u)*bfhi(t2);
      }
      p += __shfl_down(p, 4);
      p += __shfl_down(p, 2);
      p += __shfl_down(p, 1);
      if (sl == 0) redL[b][l] = p + outBias[l];
      __syncthreads();
      if (tid < 4){
        float m = redL[tid][0];
        for (int l2=1;l2<8;++l2) m = fmaxf(m, redL[tid][l2]);
        float sum = 0.f;
        for (int l2=0;l2<8;++l2) sum += __expf(redL[tid][l2]-m);
        float lse = m + __logf(sum);
        for (int l2=0;l2<8;++l2){
          float lp = redL[tid][l2] - lse;
          inpL[tid*8 + l2] = (__bf16)lp;
          if (slot == 0) dout[((long)tid*32 + (s-1))*8 + l2] = lp;
        }
      }
      __syncthreads();
    }
    if (s == 32) break;

    // P1: w0 attn logits; w1-3 gh (gate w-1), B in registers
    if (w == 0){
      f32x4 a0 = {0.f,0.f,0.f,0.f}, a1 = {0.f,0.f,0.f,0.f};
#pragma unroll
      for (int kt = 0; kt < 33; ++kt){
        bf16x8 a = dfrag(hL, inpL, row, kt, kc, 1040);
        a0 = MFMA(a, bigF[kt], a0);
        a1 = MFMA(a, bigF[33+kt], a1);
      }
      if (ln < 16){
#pragma unroll
        for (int r=0;r<4;++r) awL[r][ln] = a0[r] + abL[ln];
        if (16 + ln < 30){
#pragma unroll
          for (int r=0;r<4;++r) awL[r][16+ln] = a1[r] + abL[16+ln];
        }
      }
    } else {
      f32x4 a0 = {0.f,0.f,0.f,0.f}, a1 = {0.f,0.f,0.f,0.f};
#pragma unroll
      for (int kt = 0; kt < 32; ++kt){
        int k = kt*32 + kc;
        bf16x8 a = (row < 4) ? ld8(hL + row*1040 + k) : bzero8();
        a0 = MFMA(a, bigF[kt], a0);
        a1 = MFMA(a, bigF[33+kt], a1);
      }
      if (ln < 16){
        int gate = w - 1;
#pragma unroll
        for (int r=0;r<4;++r){
          ghL[gate][r][ln] = a0[r];
          ghL[gate][r][16+ln] = a1[r];
        }
      }
    }
    __syncthreads();
    if (tid < 4){
      float m = awL[tid][0];
      for (int t2=1;t2<30;++t2) m = fmaxf(m, awL[tid][t2]);
      float sum = 0.f;
      for (int t2=0;t2<30;++t2){ float e = __expf(awL[tid][t2]-m); awL[tid][t2] = e; sum += e; }
      float inv = 1.0f/sum;
      for (int t2=0;t2<30;++t2) awL[tid][t2] *= inv;
    }
    __syncthreads();
    // x-compute: full 512-col x per block (M-trick, no exchange); 2 c's/thread
    {
      int c0 = tid*2;
#pragma unroll 1
      for (int b = 0; b < 4; ++b){
        float z0 = cbAllL[c0], z1 = cbAllL[c0+1];
#pragma unroll
        for (int j = 0; j < 8; ++j){
          float ij = (float)inpL[b*8 + j];
          z0 += (float)WcIT[j][c0]*ij;
          z1 += (float)WcIT[j][c0+1]*ij;
        }
        const unsigned* mp = (const unsigned*)Mb + (((long)b*30)*512 + c0)/2;
#pragma unroll
        for (int t2 = 0; t2 < 30; ++t2){
          unsigned u = mp[t2*256];
          float a = awL[b][t2];
          z0 += a*bflo(u);
          z1 += a*bfhi(u);
        }
        xL[b][c0]   = (__bf16)fmaxf(z0, 0.f);
        xL[b][c0+1] = (__bf16)fmaxf(z1, 0.f);
      }
    }
    __syncthreads();
    // P3: w1-3 gi MFMA (A from xL, B from giL)
    if (w >= 1){
      int gate = w - 1;
      f32x4 a0 = {0.f,0.f,0.f,0.f}, a1 = {0.f,0.f,0.f,0.f};
#pragma unroll
      for (int kt = 0; kt < 16; ++kt){
        int k = kt*32 + kc;
        bf16x8 a = (row < 4) ? ld8(&xL[row][k]) : bzero8();
        int r0 = gate*32 + row, r1 = r0 + 16;
        bf16x8 b0 = ld8((__bf16*)((char*)giL + ((r0*1024 + k*2) ^ ((r0 & 7) << 4))));
        bf16x8 b1 = ld8((__bf16*)((char*)giL + ((r1*1024 + k*2) ^ ((r1 & 7) << 4))));
        a0 = MFMA(a, b0, a0);
        a1 = MFMA(a, b1, a1);
      }
      if (ln < 16){
#pragma unroll
        for (int r=0;r<4;++r){
          giO[gate][r][ln] = a0[r] + biL[gate][ln];
          giO[gate][r][16+ln] = a1[r] + biL[gate][16+ln];
        }
      }
    }
    __syncthreads();
    // GRU cell (own 32 cols)
    if (tid < 128){
      int b = tid >> 5, l = tid & 31, hcg = hc0 + l;
      float rr = sigf(giO[0][b][l] + ghL[0][b][l] + bhL[0][l]);
      float zz = sigf(giO[1][b][l] + ghL[1][b][l] + bhL[1][l]);
      float nn = tanhf(giO[2][b][l] + rr*(ghL[2][b][l] + bhL[2][l]));
      float hnew = (1.0f - zz)*nn + zz*hold;
      hold = hnew;
      float h2 = __shfl_down(hnew, 1);
      if (!(l & 1))
        ast(HBu + ((size_t)nxt*4 + b)*512 + (hcg >> 1), packbf(hnew, h2));
    }
  }
}

// ---------------- host ----------------
static const size_t O_BAR   = 0;          // [0..511] pyr flag slots; [512..515] cnt
static const size_t O_XSB   = 12288;
static const size_t O_WCATP = 1486848;
static const size_t O_BIASC = 3715072;
static const size_t O_HENC  = 3723264;
static const size_t O_PWHH  = 3723264;    // reuses HENC+CENC region after encoder
static const size_t O_CENC  = 5689344;
static const size_t O_CTX   = 9621504;
static const size_t O_WIHPF = 13553664;
static const size_t O_WIHPB = 21942272;
static const size_t O_BSUM  = 30330880;
static const size_t O_XPF   = 30347264;
static const size_t O_XPB   = 38211584;
static const size_t O_HPYR  = 46075904;   // [2][4][4][512] bf16 = 32KB
static const size_t O_OUTA  = 46108672;
static const size_t O_OUTB  = 48074752;
static const size_t O_ENCO  = 49057792;
static const size_t O_H0F   = 49549312;
static const size_t O_HB    = 49565696;
static const size_t O_ATTNP = 49647616;
static const size_t O_M     = 49715200;   // [4][30][512] bf16 (reuses old combP region)
// end ~49838080 (~47.5 MiB)

extern "C" void kernel_launch(void* const* d_in, const int* in_sizes, int n_in,
                              void* d_out, int out_size, void* d_ws, size_t ws_size,
                              hipStream_t stream)
{
  const float* xs    = (const float*)d_in[0];
  const int*   xlen  = (const int*)d_in[1];
  const float* eWih  = (const float*)d_in[2];
  const float* eWhh  = (const float*)d_in[3];
  const float* ebih  = (const float*)d_in[4];
  const float* ebhh  = (const float*)d_in[5];
  const float* pWihF = (const float*)d_in[6];
  const float* pWhhF = (const float*)d_in[7];
  const float* pbihF = (const float*)d_in[8];
  const float* pbhhF = (const float*)d_in[9];
  const float* pWihB = (const float*)d_in[10];
  const float* pWhhB = (const float*)d_in[11];
  const float* pbihB = (const float*)d_in[12];
  const float* pbhhB = (const float*)d_in[13];
  const float* attnW = (const float*)d_in[14];
  const float* attnb = (const float*)d_in[15];
  const float* combW = (const float*)d_in[16];
  const float* combb = (const float*)d_in[17];
  const float* gWih  = (const float*)d_in[18];
  const float* gWhh  = (const float*)d_in[19];
  const float* gbih  = (const float*)d_in[20];
  const float* gbhh  = (const float*)d_in[21];
  const float* outW  = (const float*)d_in[22];
  const float* outb  = (const float*)d_in[23];

  char* ws = (char*)d_ws;
  unsigned* BARU  = (unsigned*)(ws + O_BAR);
  __bf16* XSB     = (__bf16*)(ws + O_XSB);
  __bf16* WCATP   = (__bf16*)(ws + O_WCATP);
  float*  BIASC   = (float*)(ws + O_BIASC);
  __bf16* HENC    = (__bf16*)(ws + O_HENC);
  __bf16* PWHH    = (__bf16*)(ws + O_PWHH);
  float*  CENC    = (float*)(ws + O_CENC);
  __bf16* CTX     = (__bf16*)(ws + O_CTX);
  __bf16* WIHPF   = (__bf16*)(ws + O_WIHPF);
  __bf16* WIHPB   = (__bf16*)(ws + O_WIHPB);
  float*  BSUM    = (float*)(ws + O_BSUM);
  float*  XPF     = (float*)(ws + O_XPF);
  float*  XPB     = (float*)(ws + O_XPB);
  __bf16* HPYR    = (__bf16*)(ws + O_HPYR);
  __bf16* OUTA    = (__bf16*)(ws + O_OUTA);
  __bf16* OUTB    = (__bf16*)(ws + O_OUTB);
  float*  ENCO    = (float*)(ws + O_ENCO);
  float*  H0F     = (float*)(ws + O_H0F);
  __bf16* HB      = (__bf16*)(ws + O_HB);
  __bf16* ATTNP   = (__bf16*)(ws + O_ATTNP);
  __bf16* MB      = (__bf16*)(ws + O_M);

  initK<<<36, 256, 0, stream>>>(BARU, (unsigned*)HB);
  packSmallK<<<929, 256, 0, stream>>>(xs, eWih, eWhh, ebih, ebhh, attnW,
      XSB, WCATP, BIASC, ATTNP);

  for (int t = 0; t < 12; ++t)
    encStepK<<<dim3(30, 8), 256, 0, stream>>>(XSB, HENC, CENC, WCATP, BIASC, xlen, CTX, t);

  // layer-0 pack (standalone, after encoder frees HENC/CENC)
  packPencK<<<5168, 256, 0, stream>>>(pWihF, pWihB, pWhhF, pWhhB,
      pbihF, pbhhF, pbihB, pbhhB, WIHPF, WIHPB, BSUM, PWHH, (unsigned*)HPYR);

  const int Ts[4] = {240, 120, 60, 30};
  const __bf16* ins[4] = {CTX, OUTA, OUTB, OUTA};
  __bf16* outs[4] = {OUTA, OUTB, OUTA, OUTB};
  for (int L = 0; L < 4; ++L){
    int T = Ts[L];
    int MBk = (4*T + 63)/64;
    pencInK<<<dim3(MBk, 8, 2), 1024, 0, stream>>>(ins[L], WIHPF, WIHPB, BSUM, XPF, XPB, 4*T);
    int Ln = (L < 3) ? (L+1) : L;
    pyrRecK<<<(L < 3) ? 5168 : 32, 256, 0, stream>>>(PWHH, XPF, XPB, HPYR,
        outs[L], ENCO, H0F, HB, T, (L==3) ? 1 : 0, L, (L < 3) ? 1 : 0,
        pWihF + (long)Ln*2048*2048, pWihB + (long)Ln*2048*2048,
        pWhhF + (long)Ln*2048*512,  pWhhB + (long)Ln*2048*512,
        pbihF + Ln*2048, pbhhF + Ln*2048, pbihB + Ln*2048, pbhhB + Ln*2048,
        WIHPF, WIHPB, BSUM, PWHH, BARU + 512 + L, BARU);
  }

  precMK<<<120, 256, 0, stream>>>(combW, ENCO, MB);

  decoderK<<<32, 256, 0, stream>>>(gWih, gWhh, gbih, gbhh, combW, combb, attnb,
      outW, outb, ATTNP, MB, H0F, HB, (float*)d_out);
}

// Round 15
// 2092.658 us; speedup vs baseline: 1.0551x; 1.0551x over previous
//
#include <hip/hip_runtime.h>
#include <stdint.h>

typedef __attribute__((ext_vector_type(8))) __bf16 bf16x8;
typedef __attribute__((ext_vector_type(4))) float f32x4;
typedef __attribute__((ext_vector_type(4))) unsigned u32x4;

#define DEVI static __device__ __forceinline__
#define SENT 0xFFFFFFFFu

DEVI bf16x8 bzero8(){ bf16x8 r;
#pragma unroll
  for (int i=0;i<8;++i) r[i]=(__bf16)0.0f; return r; }

DEVI bf16x8 ld8(const __bf16* p){ return *(const bf16x8*)p; }
DEVI void st8(__bf16* p, bf16x8 v){ *(bf16x8*)p = v; }

DEVI f32x4 MFMA(bf16x8 a, bf16x8 b, f32x4 c){
  return __builtin_amdgcn_mfma_f32_16x16x32_bf16(a, b, c, 0, 0, 0);
}

DEVI float sigf(float x){ return 1.0f/(1.0f+__expf(-x)); }

// ---- agent-scope (MALL) relaxed atomics ----
DEVI void ast(unsigned* p, unsigned v){ __hip_atomic_store(p, v, __ATOMIC_RELAXED, __HIP_MEMORY_SCOPE_AGENT); }

DEVI unsigned packbf(float a, float b){
  union { __bf16 h[2]; unsigned u; } x; x.h[0]=(__bf16)a; x.h[1]=(__bf16)b; return x.u;
}
DEVI float bflo(unsigned u){ return __builtin_bit_cast(float, u<<16); }
DEVI float bfhi(unsigned u){ return __builtin_bit_cast(float, u & 0xffff0000u); }

DEVI unsigned bad4(u32x4 v){ return (v[0]==SENT)|(v[1]==SENT)|(v[2]==SENT)|(v[3]==SENT); }

// agent-coherent 16B load (bypass L1+L2, read MALL)
DEVI u32x4 ald4(const void* p){
  u32x4 v;
  asm volatile("global_load_dwordx4 %0, %1, off sc0 sc1\n\ts_waitcnt vmcnt(0)"
               : "=&v"(v) : "v"(p) : "memory");
  return v;
}
DEVI u32x4 poll4(const void* p){
  u32x4 v = ald4(p);
  while (bad4(v)){ __builtin_amdgcn_s_sleep(1); v = ald4(p); }
  return v;
}
DEVI void ald4x2(const void* p, u32x4& a, u32x4& b){
  asm volatile("global_load_dwordx4 %0, %2, off sc0 sc1\n\t"
               "global_load_dwordx4 %1, %2, off offset:16 sc0 sc1\n\t"
               "s_waitcnt vmcnt(0)"
               : "=&v"(a), "=&v"(b) : "v"(p) : "memory");
}
DEVI void poll4x2(const void* p, u32x4& a, u32x4& b){
  ald4x2(p, a, b);
  while (bad4(a) | bad4(b)){ __builtin_amdgcn_s_sleep(1); ald4x2(p, a, b); }
}

// ---------------- packing ----------------
DEVI void packGroup(const float* W, int Nsrc, int Kreal, int NT, __bf16* dst, long g){
  int kt = (int)(g / (NT*64));
  int rem = (int)(g % (NT*64));
  int nt = rem >> 6, ln = rem & 63;
  int row = nt*16 + (ln & 15);
  int col = kt*32 + ((ln >> 4) << 3);
  bf16x8 v = bzero8();
  if (row < Nsrc){
#pragma unroll
    for (int j=0;j<8;++j){ int c = col + j; if (c < Kreal) v[j] = (__bf16)W[(long)row*Kreal + c]; }
  }
  st8(dst + g*8, v);
}

DEVI void packGroupCat(const float* Wih, const float* Whh, __bf16* dst, long g){
  int kt = (int)(g / (128*64));
  int rem = (int)(g % (128*64));
  int nt = rem >> 6, ln = rem & 63;
  int prow = nt*16 + (ln & 15);
  int src = (prow & 3)*512 + (prow >> 2);
  int col = kt*32 + ((ln >> 4) << 3);
  bf16x8 v;
  if (col < 32){
#pragma unroll
    for (int j=0;j<8;++j) v[j] = (__bf16)Wih[(long)src*32 + col + j];
  } else {
#pragma unroll
    for (int j=0;j<8;++j) v[j] = (__bf16)Whh[(long)src*512 + (col-32) + j];
  }
  st8(dst + g*8, v);
}

// sentinel decoder comm buffers
__global__ void initK(unsigned* bar, unsigned* hb, unsigned* ctx, unsigned* xb){
  int g = blockIdx.x*256 + threadIdx.x;
  if (g < 3072){ bar[g] = 0u; return; }
  g -= 3072;
  if (g < 6144){ hb[2048 + g] = SENT; return; }   // HB bufs 1..3 (buf0 = h0b)
  g -= 6144;
  if (g < 8192){ ctx[g] = SENT; return; }
  g -= 8192;
  if (g < 4096){ xb[g] = SENT; return; }
}

__global__ void packSmallK(const float* __restrict__ xs, const float* __restrict__ eWih,
    const float* __restrict__ eWhh, const float* __restrict__ ebih, const float* __restrict__ ebhh,
    const float* __restrict__ attnW, const float* __restrict__ combW,
    __bf16* __restrict__ xsb, __bf16* __restrict__ wcatp, float* __restrict__ biasc,
    __bf16* __restrict__ attnp, __bf16* __restrict__ combp)
{
  long g = (long)blockIdx.x*blockDim.x + threadIdx.x;
  const long nWcat = 17L*128*64;
  const long nXs   = 92160;
  const long nBias = 2048;
  const long nAttn = 33L*2*64;
  const long nComb = 33L*32*64;
  if (g < nWcat){ packGroupCat(eWih, eWhh, wcatp, g); return; }
  g -= nWcat;
  if (g < nXs){
    const float* s = xs + g*8; bf16x8 v;
#pragma unroll
    for (int j=0;j<8;++j) v[j] = (__bf16)s[j];
    st8(xsb + g*8, v); return;
  }
  g -= nXs;
  if (g < nBias){ int src = ((int)g & 3)*512 + ((int)g >> 2); biasc[g] = ebih[src] + ebhh[src]; return; }
  g -= nBias;
  if (g < nAttn){ packGroup(attnW, 30, 1032, 2, attnp, g); return; }
  g -= nAttn;
  if (g < nComb){ packGroup(combW, 512, 1032, 32, combp, g); return; }
}

// pack pyramid layer: Wih (MFMA-B layout), biases, HPYR sentinel init,
// and Whh -> per-(dir,slot,wave) register-fragment layout (bf16)
__global__ void packPencK(const float* __restrict__ Wf, const float* __restrict__ Wb,
    const float* __restrict__ WhF, const float* __restrict__ WhB,
    const float* __restrict__ bihf, const float* __restrict__ bhhf,
    const float* __restrict__ bihb, const float* __restrict__ bhhb,
    __bf16* __restrict__ pf, __bf16* __restrict__ pb, float* __restrict__ bsum,
    __bf16* __restrict__ pwhh, unsigned* __restrict__ hpy)
{
  long g = (long)blockIdx.x*blockDim.x + threadIdx.x;
  const long nW = 64L*128*64;
  if (g < nW){ packGroup(Wf, 2048, 2048, 128, pf, g); return; }
  g -= nW;
  if (g < nW){ packGroup(Wb, 2048, 2048, 128, pb, g); return; }
  g -= nW;
  if (g < 2048){ bsum[g] = bihf[g] + bhhf[g]; return; }
  g -= 2048;
  if (g < 2048){ bsum[2048+g] = bihb[g] + bhhb[g]; return; }
  g -= 2048;
  if (g < 8192){  // [2dir][4buf][4][512] bf16 = 8192 dwords; buf0=0, bufs1-3=SENT
    hpy[g] = ((g >> 10) & 3) ? SENT : 0u;
    return;
  }
  g -= 8192;
  if (g < 262144){
    int lane = (int)(g & 63);
    int f    = (int)((g >> 6) & 31);
    int w    = (int)((g >> 11) & 3);
    int slot = (int)((g >> 13) & 15);
    int dir  = (int)((g >> 17) & 1);
    int kt = f >> 1, nt = f & 1;
    int row16 = lane & 15, kch = lane >> 4;
    int srow = w*512 + slot*32 + nt*16 + row16;
    int scol = kt*32 + kch*8;
    const float* W = dir ? WhB : WhF;
    bf16x8 v;
#pragma unroll
    for (int j=0;j<8;++j) v[j] = (__bf16)W[(long)srow*512 + scol + j];
    st8(pwhh + g*8, v);
  }
}

// ---------------- encoder step ----------------
__global__ __launch_bounds__(256, 1) void encStepK(
    const __bf16* __restrict__ xsb,
    __bf16* __restrict__ henc,
    float* __restrict__ cenc,
    const __bf16* __restrict__ wcatp,
    const float* __restrict__ biasc,
    const int* __restrict__ xlen,
    __bf16* __restrict__ ctx,
    int t)
{
  __shared__ float glds[64][260];
  const int tid = threadIdx.x;
  const int w = tid >> 6, ln = tid & 63;
  const int m0 = blockIdx.x * 64;
  const int nb = blockIdx.y;
  f32x4 acc[16];
#pragma unroll
  for (int i=0;i<16;++i) acc[i] = (f32x4){0.f,0.f,0.f,0.f};

  const int arow = m0 + w*16 + (ln & 15);
  const int kc = (ln >> 4) << 3;
  const int ktEnd = (t == 0) ? 1 : 17;
  for (int kt = 0; kt < ktEnd; ++kt){
    bf16x8 a;
    if (kt == 0) a = ld8(xsb + ((long)t*1920 + arow)*32 + kc);
    else         a = ld8(henc + (long)arow*512 + (kt-1)*32 + kc);
    const __bf16* bp = wcatp + (((long)kt*128 + nb*16)*64 + ln)*8;
#pragma unroll
    for (int n2 = 0; n2 < 16; ++n2){
      bf16x8 b = ld8(bp + (long)n2*512);
      acc[n2] = MFMA(a, b, acc[n2]);
    }
  }
  const int r4 = (ln >> 4) << 2;
#pragma unroll
  for (int n2 = 0; n2 < 16; ++n2){
#pragma unroll
    for (int r = 0; r < 4; ++r)
      glds[w*16 + r4 + r][n2*16 + (ln & 15)] = acc[n2][r];
  }
  __syncthreads();
  for (int it = 0; it < 16; ++it){
    int idx = tid + it*256;
    int mrow = idx >> 6, hcl = idx & 63;
    int n = m0 + mrow;
    int hcg = nb*64 + hcl;
    float ig = glds[mrow][hcl*4+0] + biasc[nb*256 + hcl*4+0];
    float fg = glds[mrow][hcl*4+1] + biasc[nb*256 + hcl*4+1];
    float gg = glds[mrow][hcl*4+2] + biasc[nb*256 + hcl*4+2];
    float og = glds[mrow][hcl*4+3] + biasc[nb*256 + hcl*4+3];
    float c_old = (t == 0) ? 0.0f : cenc[(long)n*512 + hcg];
    float cn = sigf(fg)*c_old + sigf(ig)*tanhf(gg);
    float h  = sigf(og)*tanhf(cn);
    cenc[(long)n*512 + hcg] = cn;
    henc[(long)n*512 + hcg] = (__bf16)h;
    if (xlen[n] - 1 == t){
      ctx[(long)n*1024 + hcg]       = (__bf16)h;
      ctx[(long)n*1024 + 512 + hcg] = (__bf16)cn;
    }
  }
}

// ---------------- pyramid input GEMM ----------------
__global__ __launch_bounds__(1024) void pencInK(
   const __bf16* __restrict__ inb,
   const __bf16* __restrict__ wpf, const __bf16* __restrict__ wpb,
   const float* __restrict__ bsum,
   float* __restrict__ xpf, float* __restrict__ xpb,
   int M)
{
  const int tid = threadIdx.x, ln = tid & 63, wv = tid >> 6;
  const int rg = wv >> 2, cg = wv & 3;
  const int dir = blockIdx.z;
  const int m0 = blockIdx.x*64 + rg*16;
  const int nb = blockIdx.y;
  const __bf16* wp = dir ? wpb : wpf;
  float* xp = dir ? xpb : xpf;
  const float* bs = bsum + dir*2048;
  f32x4 acc[4];
#pragma unroll
  for (int i=0;i<4;++i) acc[i] = (f32x4){0.f,0.f,0.f,0.f};
  const int arow = m0 + (ln & 15);
  const int kc = (ln >> 4) << 3;
  const bool aok = arow < M;
  for (int kt = 0; kt < 64; ++kt){
    bf16x8 a = aok ? ld8(inb + (long)arow*2048 + kt*32 + kc) : bzero8();
    const __bf16* bp = wp + (((long)kt*128 + nb*16 + cg*4)*64 + ln)*8;
#pragma unroll
    for (int q = 0; q < 4; ++q){
      bf16x8 b = ld8(bp + (long)q*512);
      acc[q] = MFMA(a, b, acc[q]);
    }
  }
  const int r4 = (ln >> 4) << 2;
#pragma unroll
  for (int q = 0; q < 4; ++q){
    int col = (nb*16 + cg*4 + q)*16 + (ln & 15);
#pragma unroll
    for (int r = 0; r < 4; ++r){
      int rowo = m0 + r4 + r;
      if (rowo < M) xp[(long)rowo*2048 + col] = acc[q][r] + bs[col];
    }
  }
}

// ---------------- pyramid recurrence: persistent, register-B, sentinel poll ----------------
__global__ __launch_bounds__(256, 1) void pyrRecK(
  const __bf16* __restrict__ pwhh,
  const float* __restrict__ xpf, const float* __restrict__ xpb,
  __bf16* __restrict__ hbuf,
  __bf16* __restrict__ outb,
  float* __restrict__ outf,
  float* __restrict__ h0f, __bf16* __restrict__ h0b,
  int T, int isLast)
{
  __shared__ __align__(16) __bf16 hsL[2][4*528];   // padded: stride 528 el (2-way max)
  __shared__ float glds[4][4][32];
  const int tid = threadIdx.x, ln = tid & 63, w = tid >> 6;
  const int bk = blockIdx.x;
  const int dir = bk >> 4, slot = bk & 15;
  const int hc0 = slot * 32;
  const float* xp = dir ? xpb : xpf;
  unsigned* hbu = (unsigned*)hbuf;

  bf16x8 BF[32];
  {
    const __bf16* wb = pwhh + ((((size_t)(dir*16 + slot)*4 + w)*32)*64 + ln)*8;
#pragma unroll
    for (int f = 0; f < 32; ++f) BF[f] = ld8(wb + (size_t)f*512);
  }

  const int arow = ln & 15;
  const int kc = (ln >> 4) << 3;
  float cv = 0.0f;
  float x0=0.f,x1=0.f,x2=0.f,x3=0.f;
  if (tid < 128){
    int pos0 = dir ? (T-1) : 0;
    const float* xr = xp + ((size_t)((tid>>5)*T + pos0))*2048 + hc0 + (tid & 31);
    x0 = xr[0]; x1 = xr[512]; x2 = xr[1024]; x3 = xr[1536];
  }

  for (int t = 0; t < T; ++t){
    int cur = t & 3, nxt = (t+1) & 3, clr = (t+2) & 3;
    int pos = dir ? (T-1-t) : t;
    // poll h(t) -> hsL[t&1] (padded remap, element units)
    {
      u32x4 v = poll4((const char*)hbuf + (size_t)(dir*4 + cur)*4096 + tid*16);
      int e0 = tid*8, r = e0 >> 9, o = e0 & 511;
      *(u32x4*)(hsL[t & 1] + r*528 + o) = v;
    }
    __syncthreads();
    if (tid < 64){
      int b = tid >> 4, i = tid & 15;
      ast(hbu + ((size_t)(dir*4 + clr)*4 + b)*256 + (hc0 >> 1) + i, SENT);
    }
    // MFMA with register-resident B; 4 accumulator chains
    const __bf16* hs = hsL[t & 1];
    f32x4 a0 = {0.f,0.f,0.f,0.f}, a1 = a0, a2 = a0, a3 = a0;
#pragma unroll
    for (int kt = 0; kt < 16; kt += 2){
      bf16x8 aA = (arow < 4) ? ld8(hs + arow*528 + kt*32 + kc) : bzero8();
      bf16x8 aB = (arow < 4) ? ld8(hs + arow*528 + (kt+1)*32 + kc) : bzero8();
      a0 = MFMA(aA, BF[kt*2+0], a0);
      a1 = MFMA(aA, BF[kt*2+1], a1);
      a2 = MFMA(aB, BF[kt*2+2], a2);
      a3 = MFMA(aB, BF[kt*2+3], a3);
    }
    a0 += a2; a1 += a3;
    // prefetch x(t+1)
    float xn0=0.f,xn1=0.f,xn2=0.f,xn3=0.f;
    if (t+1 < T && tid < 128){
      int pos2 = dir ? (T-2-t) : (t+1);
      const float* xr = xp + ((size_t)((tid>>5)*T + pos2))*2048 + hc0 + (tid & 31);
      xn0 = xr[0]; xn1 = xr[512]; xn2 = xr[1024]; xn3 = xr[1536];
    }
    if (ln < 16){
#pragma unroll
      for (int r=0;r<4;++r){ glds[w][r][ln] = a0[r]; glds[w][r][16+ln] = a1[r]; }
    }
    __syncthreads();
    if (tid < 128){
      int b = tid >> 5, hcl = tid & 31, hcg = hc0 + hcl;
      float ig = glds[0][b][hcl] + x0;
      float fg = glds[1][b][hcl] + x1;
      float gg = glds[2][b][hcl] + x2;
      float og = glds[3][b][hcl] + x3;
      cv = sigf(fg)*cv + sigf(ig)*tanhf(gg);
      float h = sigf(og)*tanhf(cv);
      float hn = __shfl_down(h, 1);
      if (!(hcl & 1))
        ast(hbu + ((size_t)(dir*4 + nxt)*4 + b)*256 + (hcg >> 1), packbf(h, hn));
      if (!isLast){
        outb[((long)(b*T + pos))*1024 + dir*512 + hcg] = (__bf16)h;
      } else {
        outf[((long)(b*T + pos))*1024 + dir*512 + hcg] = h;
        if (t == T-1){
          h0f[b*1024 + dir*512 + hcg] = h;
          h0b[b*1024 + dir*512 + hcg] = (__bf16)h;
        }
      }
    }
    x0=xn0; x1=xn1; x2=xn2; x3=xn3;
  }
}

// ---------------- decoder: persistent, 32 blocks, sentinel data-poll ----------------
DEVI bf16x8 dfrag(const __bf16* base, const __bf16* inp, int row, int kt, int kc, int stride){
  if (row >= 4) return bzero8();
  int k = kt*32 + kc;
  if (k == 0) return ld8(inp + row*8);
  int off = k - 8;
  return (off < 1024) ? ld8(base + row*stride + off) : bzero8();
}

__global__ __launch_bounds__(256, 1) void decoderK(
  const float* __restrict__ gWih,   // [3072][512]
  const float* __restrict__ gWhh,   // [3072][1024]
  const float* __restrict__ gbih, const float* __restrict__ gbhh,
  const float* __restrict__ combBias, const float* __restrict__ attnBias,
  const float* __restrict__ outW, const float* __restrict__ outBias,
  const __bf16* __restrict__ attnP, const __bf16* __restrict__ combP,
  const float* __restrict__ encOut,  // [4][30][1024] f32
  const float* __restrict__ h0f,
  __bf16* __restrict__ HB,           // [4buf][4][1024]
  __bf16* __restrict__ CTXB,         // [4buf][4][1024]
  __bf16* __restrict__ XB,           // [4buf][4][512]
  float* __restrict__ dout)
{
  __shared__ __align__(16) __bf16 giL[96*512];     // 96 KB
  __shared__ __align__(16) __bf16 outWL[8*1040];   // padded stride 520 dwords
  __shared__ __align__(16) __bf16 hL[4*1040];      // padded stride 520 dwords
  __shared__ __align__(16) __bf16 ctxvL[4][1056];
  __shared__ __align__(16) __bf16 xL[4][528];
  __shared__ __bf16 encOutL[4][30][32];
  __shared__ __align__(16) __bf16 inpL[32];
  __shared__ float awL[4][30];
  __shared__ float redL[4][8];
  __shared__ float ghL[3][4][32];
  __shared__ float giO[3][4][32];
  __shared__ float combL[4][4][16];
  __shared__ float biL[3][32], bhL[3][32];
  __shared__ float abL[30];
  __shared__ float cbL[16];

  const int tid = threadIdx.x, ln = tid & 63, w = tid >> 6;
  const int slot = blockIdx.x;
  const int hc0 = slot * 32;
  unsigned* HBu = (unsigned*)HB;
  unsigned* CTXu = (unsigned*)CTXB;
  unsigned* XBu = (unsigned*)XB;

  // gi weights -> LDS (3 gates x 32 own cols = 96 rows x 512, XOR swizzled)
  for (int it = 0; it < 24; ++it){
    int g = it*256 + tid;
    int rho = g >> 6, c8 = g & 63;
    int gate = rho >> 5, r = rho & 31;
    const float* s = gWih + ((long)(gate*1024 + hc0 + r))*512 + c8*8;
    bf16x8 v;
#pragma unroll
    for (int j=0;j<8;++j) v[j] = (__bf16)s[j];
    st8((__bf16*)((char*)giL + ((rho*1024 + c8*16) ^ ((rho & 7) << 4))), v);
  }
  for (int it = 0; it < 32; ++it){
    int g = it*256 + tid;
    int r = g >> 10, c = g & 1023;
    outWL[r*1040 + c] = (__bf16)outW[g];
  }
  for (int idx = tid; idx < 3840; idx += 256){
    int b = idx/960, rem = idx%960;
    int t2 = rem >> 5, dl = rem & 31;
    encOutL[b][t2][dl] = (__bf16)encOut[((long)b*30 + t2)*1024 + hc0 + dl];
  }
  if (tid < 96){
    int g2 = tid >> 5, l = tid & 31;
    biL[g2][l] = gbih[g2*1024 + hc0 + l];
    bhL[g2][l] = gbhh[g2*1024 + hc0 + l];
  }
  if (tid < 30) abL[tid] = attnBias[tid];
  if (tid < 16) cbL[tid] = combBias[slot*16 + tid];

  const int row = ln & 15, kc = (ln >> 4) << 3;
  bf16x8 bigF[66];
  if (w == 0){
#pragma unroll
    for (int nt = 0; nt < 2; ++nt)
#pragma unroll
      for (int kt = 0; kt < 33; ++kt)
        bigF[nt*33 + kt] = ld8(attnP + (((size_t)kt*2 + nt)*64 + ln)*8);
  } else {
    int gate = w - 1;
#pragma unroll
    for (int nt = 0; nt < 2; ++nt)
#pragma unroll
      for (int kt = 0; kt < 32; ++kt){
        const float* s = gWhh + ((long)(gate*1024 + hc0 + nt*16 + row))*1024 + kt*32 + kc;
        bf16x8 v;
#pragma unroll
        for (int j=0;j<8;++j) v[j] = (__bf16)s[j];
        bigF[nt*33 + kt] = v;
      }
  }
  const int kt0c = (w == 0) ? 0 : (w*8 + 1);
  const int nkt = (w == 0) ? 9 : 8;
  bf16x8 combF[9];
#pragma unroll
  for (int i = 0; i < 9; ++i)
    combF[i] = (i < nkt) ? ld8(combP + (((size_t)(kt0c+i)*32 + slot)*64 + ln)*8) : bzero8();

  float hold = 0.f;
  if (tid < 128) hold = h0f[(tid>>5)*1024 + hc0 + (tid & 31)];
  __syncthreads();

  for (int s = 0; s <= 32; ++s){
    int cur = s & 3, nxt = (s+1) & 3, clr = (s+2) & 3;
    // poll h(s) -> hL (padded remap, element units)
    {
      u32x4 q0, q1;
      poll4x2((const char*)HB + (size_t)cur*8192 + tid*32, q0, q1);
      int e0 = tid*16, r0 = e0 >> 10, o0 = e0 & 1023;
      u32x4* d = (u32x4*)(hL + r0*1040 + o0);
      d[0] = q0; d[1] = q1;
    }
    __syncthreads();
    // re-sentinel step s+2 h/ctx/x buffers (own cols) — after the poll
    if (tid < 64){
      int b = tid >> 4, i = tid & 15;
      ast(HBu  + ((size_t)clr*4 + b)*512 + (hc0 >> 1) + i, SENT);
      ast(CTXu + ((size_t)clr*4 + b)*512 + (hc0 >> 1) + i, SENT);
    }
    if (tid < 32){
      int b = tid >> 3, i = tid & 7;
      ast(XBu + ((size_t)clr*4 + b)*256 + ((slot*16) >> 1) + i, SENT);
    }
    if (s == 0){
      if (tid < 32) inpL[tid] = (__bf16)0.0f;
      __syncthreads();
    } else {
      // logits: conflict-free interleaved dot-product (padded strides)
      int o = tid >> 3, sl = tid & 7;
      int b = o >> 3, l = o & 7;
      const unsigned* hrow = (const unsigned*)hL + b*520;
      const unsigned* wrow = (const unsigned*)outWL + l*520;
      float p = 0.f;
#pragma unroll 8
      for (int j = 0; j < 64; ++j){
        unsigned u = hrow[sl + 8*j], t2 = wrow[sl + 8*j];
        p += bflo(u)*bflo(t2) + bfhi(u)*bfhi(t2);
      }
      p += __shfl_down(p, 4);
      p += __shfl_down(p, 2);
      p += __shfl_down(p, 1);
      if (sl == 0) redL[b][l] = p + outBias[l];
      __syncthreads();
      if (tid < 4){
        float m = redL[tid][0];
        for (int l2=1;l2<8;++l2) m = fmaxf(m, redL[tid][l2]);
        float sum = 0.f;
        for (int l2=0;l2<8;++l2) sum += __expf(redL[tid][l2]-m);
        float lse = m + __logf(sum);
        for (int l2=0;l2<8;++l2){
          float lp = redL[tid][l2] - lse;
          inpL[tid*8 + l2] = (__bf16)lp;
          if (slot == 0) dout[((long)tid*32 + (s-1))*8 + l2] = lp;
        }
      }
      __syncthreads();
    }
    if (s == 32) break;

    // P1: w0 attn logits; w1-3 gh (gate w-1), B in registers
    if (w == 0){
      f32x4 a0 = {0.f,0.f,0.f,0.f}, a1 = {0.f,0.f,0.f,0.f};
#pragma unroll
      for (int kt = 0; kt < 33; ++kt){
        bf16x8 a = dfrag(hL, inpL, row, kt, kc, 1040);
        a0 = MFMA(a, bigF[kt], a0);
        a1 = MFMA(a, bigF[33+kt], a1);
      }
      if (ln < 16){
#pragma unroll
        for (int r=0;r<4;++r) awL[r][ln] = a0[r] + abL[ln];
        if (16 + ln < 30){
#pragma unroll
          for (int r=0;r<4;++r) awL[r][16+ln] = a1[r] + abL[16+ln];
        }
      }
    } else {
      f32x4 a0 = {0.f,0.f,0.f,0.f}, a1 = {0.f,0.f,0.f,0.f};
#pragma unroll
      for (int kt = 0; kt < 32; ++kt){
        int k = kt*32 + kc;
        bf16x8 a = (row < 4) ? ld8(hL + row*1040 + k) : bzero8();
        a0 = MFMA(a, bigF[kt], a0);
        a1 = MFMA(a, bigF[33+kt], a1);
      }
      if (ln < 16){
        int gate = w - 1;
#pragma unroll
        for (int r=0;r<4;++r){
          ghL[gate][r][ln] = a0[r];
          ghL[gate][r][16+ln] = a1[r];
        }
      }
    }
    __syncthreads();
    if (tid < 4){
      float m = awL[tid][0];
      for (int t2=1;t2<30;++t2) m = fmaxf(m, awL[tid][t2]);
      float sum = 0.f;
      for (int t2=0;t2<30;++t2){ float e = __expf(awL[tid][t2]-m); awL[tid][t2] = e; sum += e; }
      float inv = 1.0f/sum;
      for (int t2=0;t2<30;++t2) awL[tid][t2] *= inv;
    }
    __syncthreads();
    // produce ctxv (own 32 cols)
    if (tid < 128){
      int b = tid >> 5, dl = tid & 31;
      float sum = 0.f;
      for (int t2=0;t2<30;++t2) sum += awL[b][t2]*(float)encOutL[b][t2][dl];
      float sn = __shfl_down(sum, 1);
      if (!(dl & 1))
        ast(CTXu + ((size_t)cur*4 + b)*512 + ((hc0 + dl) >> 1), packbf(sum, sn));
    }
    // batched poll ctxv -> ctxvL
    {
      u32x4 q0, q1;
      poll4x2((const char*)CTXB + (size_t)cur*8192 + tid*32, q0, q1);
      u32x4* dst = (u32x4*)((char*)&ctxvL[0][0] + (tid>>6)*2112 + (tid&63)*32);
      dst[0] = q0; dst[1] = q1;
    }
    __syncthreads();
    // P2: comb (own 16 out cols), K split across 4 waves
    {
      f32x4 acc = {0.f,0.f,0.f,0.f};
#pragma unroll
      for (int i = 0; i < 9; ++i){
        if (i < nkt){
          bf16x8 a = dfrag(&ctxvL[0][0], inpL, row, kt0c+i, kc, 1056);
          acc = MFMA(a, combF[i], acc);
        }
      }
      if (ln < 16){
#pragma unroll
        for (int r=0;r<4;++r) combL[w][r][ln] = acc[r];
      }
    }
    __syncthreads();
    if (tid < 64){
      int r = tid >> 4, l = tid & 15, col = slot*16 + l;
      float x = combL[0][r][l] + combL[1][r][l] + combL[2][r][l] + combL[3][r][l] + cbL[l];
      x = fmaxf(x, 0.0f);
      float xn = __shfl_down(x, 1);
      if (!(l & 1))
        ast(XBu + ((size_t)cur*4 + r)*256 + (col >> 1), packbf(x, xn));
    }
    // batched poll x -> xL
    {
      u32x4 v = poll4((const char*)XB + (size_t)cur*4096 + tid*16);
      u32x4* dst = (u32x4*)((char*)&xL[0][0] + (tid>>6)*1056 + (tid&63)*16);
      dst[0] = v;
    }
    __syncthreads();
    // P3: w1-3 gi MFMA (A from xL, B from giL)
    if (w >= 1){
      int gate = w - 1;
      f32x4 a0 = {0.f,0.f,0.f,0.f}, a1 = {0.f,0.f,0.f,0.f};
#pragma unroll
      for (int kt = 0; kt < 16; ++kt){
        int k = kt*32 + kc;
        bf16x8 a = (row < 4) ? ld8(&xL[row][k]) : bzero8();
        int r0 = gate*32 + row, r1 = r0 + 16;
        bf16x8 b0 = ld8((__bf16*)((char*)giL + ((r0*1024 + k*2) ^ ((r0 & 7) << 4))));
        bf16x8 b1 = ld8((__bf16*)((char*)giL + ((r1*1024 + k*2) ^ ((r1 & 7) << 4))));
        a0 = MFMA(a, b0, a0);
        a1 = MFMA(a, b1, a1);
      }
      if (ln < 16){
#pragma unroll
        for (int r=0;r<4;++r){
          giO[gate][r][ln] = a0[r] + biL[gate][ln];
          giO[gate][r][16+ln] = a1[r] + biL[gate][16+ln];
        }
      }
    }
    __syncthreads();
    // GRU cell (own 32 cols)
    if (tid < 128){
      int b = tid >> 5, l = tid & 31, hcg = hc0 + l;
      float rr = sigf(giO[0][b][l] + ghL[0][b][l] + bhL[0][l]);
      float zz = sigf(giO[1][b][l] + ghL[1][b][l] + bhL[1][l]);
      float nn = tanhf(giO[2][b][l] + rr*(ghL[2][b][l] + bhL[2][l]));
      float hnew = (1.0f - zz)*nn + zz*hold;
      hold = hnew;
      float h2 = __shfl_down(hnew, 1);
      if (!(l & 1))
        ast(HBu + ((size_t)nxt*4 + b)*512 + (hcg >> 1), packbf(hnew, h2));
    }
  }
}

// ---------------- host ----------------
static const size_t O_BAR   = 0;
static const size_t O_XSB   = 12288;
static const size_t O_WCATP = 1486848;
static const size_t O_BIASC = 3715072;
static const size_t O_HENC  = 3723264;
static const size_t O_PWHH  = 3723264;    // reuses HENC+CENC region after encoder
static const size_t O_CENC  = 5689344;
static const size_t O_CTX   = 9621504;
static const size_t O_WIHPF = 13553664;
static const size_t O_WIHPB = 21942272;
static const size_t O_BSUM  = 30330880;
static const size_t O_XPF   = 30347264;
static const size_t O_XPB   = 38211584;
static const size_t O_HPYR  = 46075904;   // [2][4][4][512] bf16 = 32KB
static const size_t O_OUTA  = 46108672;
static const size_t O_OUTB  = 48074752;
static const size_t O_ENCO  = 49057792;
static const size_t O_H0F   = 49549312;
static const size_t O_HB    = 49565696;
static const size_t O_CTXB  = 49598464;
static const size_t O_XB    = 49631232;
static const size_t O_ATTNP = 49647616;
static const size_t O_COMBP = 49715200;
// end 50796544 (~48.4 MiB)

extern "C" void kernel_launch(void* const* d_in, const int* in_sizes, int n_in,
                              void* d_out, int out_size, void* d_ws, size_t ws_size,
                              hipStream_t stream)
{
  const float* xs    = (const float*)d_in[0];
  const int*   xlen  = (const int*)d_in[1];
  const float* eWih  = (const float*)d_in[2];
  const float* eWhh  = (const float*)d_in[3];
  const float* ebih  = (const float*)d_in[4];
  const float* ebhh  = (const float*)d_in[5];
  const float* pWihF = (const float*)d_in[6];
  const float* pWhhF = (const float*)d_in[7];
  const float* pbihF = (const float*)d_in[8];
  const float* pbhhF = (const float*)d_in[9];
  const float* pWihB = (const float*)d_in[10];
  const float* pWhhB = (const float*)d_in[11];
  const float* pbihB = (const float*)d_in[12];
  const float* pbhhB = (const float*)d_in[13];
  const float* attnW = (const float*)d_in[14];
  const float* attnb = (const float*)d_in[15];
  const float* combW = (const float*)d_in[16];
  const float* combb = (const float*)d_in[17];
  const float* gWih  = (const float*)d_in[18];
  const float* gWhh  = (const float*)d_in[19];
  const float* gbih  = (const float*)d_in[20];
  const float* gbhh  = (const float*)d_in[21];
  const float* outW  = (const float*)d_in[22];
  const float* outb  = (const float*)d_in[23];

  char* ws = (char*)d_ws;
  unsigned* BARU  = (unsigned*)(ws + O_BAR);
  __bf16* XSB     = (__bf16*)(ws + O_XSB);
  __bf16* WCATP   = (__bf16*)(ws + O_WCATP);
  float*  BIASC   = (float*)(ws + O_BIASC);
  __bf16* HENC    = (__bf16*)(ws + O_HENC);
  __bf16* PWHH    = (__bf16*)(ws + O_PWHH);
  float*  CENC    = (float*)(ws + O_CENC);
  __bf16* CTX     = (__bf16*)(ws + O_CTX);
  __bf16* WIHPF   = (__bf16*)(ws + O_WIHPF);
  __bf16* WIHPB   = (__bf16*)(ws + O_WIHPB);
  float*  BSUM    = (float*)(ws + O_BSUM);
  float*  XPF     = (float*)(ws + O_XPF);
  float*  XPB     = (float*)(ws + O_XPB);
  __bf16* HPYR    = (__bf16*)(ws + O_HPYR);
  __bf16* OUTA    = (__bf16*)(ws + O_OUTA);
  __bf16* OUTB    = (__bf16*)(ws + O_OUTB);
  float*  ENCO    = (float*)(ws + O_ENCO);
  float*  H0F     = (float*)(ws + O_H0F);
  __bf16* HB      = (__bf16*)(ws + O_HB);
  __bf16* CTXB    = (__bf16*)(ws + O_CTXB);
  __bf16* XB      = (__bf16*)(ws + O_XB);
  __bf16* ATTNP   = (__bf16*)(ws + O_ATTNP);
  __bf16* COMBP   = (__bf16*)(ws + O_COMBP);

  initK<<<84, 256, 0, stream>>>(BARU, (unsigned*)HB, (unsigned*)CTXB, (unsigned*)XB);
  packSmallK<<<1193, 256, 0, stream>>>(xs, eWih, eWhh, ebih, ebhh, attnW, combW,
      XSB, WCATP, BIASC, ATTNP, COMBP);

  for (int t = 0; t < 12; ++t)
    encStepK<<<dim3(30, 8), 256, 0, stream>>>(XSB, HENC, CENC, WCATP, BIASC, xlen, CTX, t);

  const int Ts[4] = {240, 120, 60, 30};
  const __bf16* ins[4] = {CTX, OUTA, OUTB, OUTA};
  __bf16* outs[4] = {OUTA, OUTB, OUTA, OUTB};
  for (int L = 0; L < 4; ++L){
    int T = Ts[L];
    packPencK<<<5168, 256, 0, stream>>>(pWihF + (long)L*2048*2048, pWihB + (long)L*2048*2048,
        pWhhF + (long)L*2048*512, pWhhB + (long)L*2048*512,
        pbihF + L*2048, pbhhF + L*2048, pbihB + L*2048, pbhhB + L*2048,
        WIHPF, WIHPB, BSUM, PWHH, (unsigned*)HPYR);
    int MBk = (4*T + 63)/64;
    pencInK<<<dim3(MBk, 8, 2), 1024, 0, stream>>>(ins[L], WIHPF, WIHPB, BSUM, XPF, XPB, 4*T);
    pyrRecK<<<32, 256, 0, stream>>>(PWHH, XPF, XPB, HPYR, outs[L], ENCO, H0F, HB,
        T, (L==3) ? 1 : 0);
  }

  decoderK<<<32, 256, 0, stream>>>(gWih, gWhh, gbih, gbhh, combb, attnb, outW, outb,
      ATTNP, COMBP, ENCO, H0F, HB, CTXB, XB, (float*)d_out);
}